// Round 2
// baseline (2577.880 us; speedup 1.0000x reference)
//
#include <hip/hip_runtime.h>
#include <hip/hip_bf16.h>

#define DEV __device__ __forceinline__

DEV float lrelu_(float x){ return x > 0.f ? x : 0.01f * x; }
DEV float ssp_(float x){ float sp = fmaxf(x, 0.f) + log1pf(__expf(-fabsf(x))); return sp - 0.69314718055994530942f; }
DEV float sigm_(float x){ return 1.f / (1.f + __expf(-x)); }

// ---------------- generic row-GEMV:  Y[r,c] = act(sum_k X[r,k]*W[k,c] + b[c]) ----------------
// ACT: 0=none 1=lrelu 2=relu
template<int K, int C, int ACT>
__global__ __launch_bounds__(256) void lin_kernel(const float* __restrict__ X,
                                                  const float* __restrict__ W,
                                                  const float* __restrict__ B,
                                                  float* __restrict__ Y, int nrows)
{
    constexpr int ROWS = 256 / C;
    __shared__ float Ws[K * C];
    __shared__ float bs[C];
    __shared__ float Xs[ROWS * K];
    for (int i = threadIdx.x; i < K * C; i += 256) Ws[i] = W[i];
    if (threadIdx.x < C) bs[threadIdx.x] = B[threadIdx.x];
    __syncthreads();
    const int r = threadIdx.x / C, c = threadIdx.x % C;
    for (int base = blockIdx.x * ROWS; base < nrows; base += gridDim.x * ROWS) {
        __syncthreads();
        for (int i = threadIdx.x; i < ROWS * K; i += 256) {
            int rr = base + i / K;
            Xs[i] = (rr < nrows) ? X[(size_t)rr * K + i % K] : 0.f;
        }
        __syncthreads();
        int row = base + r;
        if (row < nrows) {
            float acc = bs[c];
            #pragma unroll
            for (int k = 0; k < K; k++) acc += Xs[r * K + k] * Ws[k * C + c];
            if (ACT == 1) acc = lrelu_(acc);
            else if (ACT == 2) acc = fmaxf(acc, 0.f);
            Y[(size_t)row * C + c] = acc;
        }
    }
}

// ---------------- degrees ----------------
__global__ __launch_bounds__(256) void deg_kernel(const int* __restrict__ src, const int* __restrict__ dst,
                                                  int* __restrict__ degs, int* __restrict__ degd, int np)
{
    int p = blockIdx.x * 256 + threadIdx.x;
    if (p < np) { atomicAdd(&degs[src[p]], 1); atomicAdd(&degd[dst[p]], 1); }
}

__global__ __launch_bounds__(256) void norm_kernel(int* __restrict__ arr, int n)
{
    int i = blockIdx.x * 256 + threadIdx.x;
    if (i < n) {
        int v = arr[i]; if (v < 1) v = 1;
        arr[i] = __float_as_int(rsqrtf((float)v));
    }
}

// ---------------- edge weights for all 3 layers ----------------
__global__ __launch_bounds__(256) void edge_ew_kernel(const float* __restrict__ in_edge,
                                                      const float* __restrict__ elW, const float* __restrict__ elb,
                                                      const float* __restrict__ gW, const float* __restrict__ gb,
                                                      float* __restrict__ ew3, int ne)
{
    __shared__ float W[32], B[8], G[24], Gb[3];
    if (threadIdx.x < 32) W[threadIdx.x] = elW[threadIdx.x];
    if (threadIdx.x < 8)  B[threadIdx.x] = elb[threadIdx.x];
    if (threadIdx.x < 24) G[threadIdx.x] = gW[threadIdx.x];
    if (threadIdx.x < 3)  Gb[threadIdx.x] = gb[threadIdx.x];
    __syncthreads();
    for (int e = blockIdx.x * 256 + threadIdx.x; e < ne; e += gridDim.x * 256) {
        float x0 = in_edge[(size_t)e * 4 + 0], x1 = in_edge[(size_t)e * 4 + 1];
        float x2 = in_edge[(size_t)e * 4 + 2], x3 = in_edge[(size_t)e * 4 + 3];
        float ef[8];
        #pragma unroll
        for (int j = 0; j < 8; j++)
            ef[j] = lrelu_(B[j] + x0 * W[j] + x1 * W[8 + j] + x2 * W[16 + j] + x3 * W[24 + j]);
        #pragma unroll
        for (int i = 0; i < 3; i++) {
            float a = Gb[i];
            #pragma unroll
            for (int j = 0; j < 8; j++) a += ef[j] * G[i * 8 + j];
            ew3[(size_t)i * ne + e] = sigm_(a);
        }
    }
}

// ---------------- pins GraphConv scatter:  agg[dst] += node*srcnorm ----------------
__global__ __launch_bounds__(256) void pins_scatter(const float* __restrict__ nf, const float* __restrict__ snorm,
                                                    const int* __restrict__ src, const int* __restrict__ dst,
                                                    float* __restrict__ agg, int np)
{
    int idx = blockIdx.x * 256 + threadIdx.x;
    int p = idx >> 6; if (p >= np) return;
    int c = idx & 63;
    int s = src[p], d = dst[p];
    unsafeAtomicAdd(&agg[(size_t)d * 64 + c], nf[(size_t)s * 64 + c] * snorm[s]);
}

// ---------------- net update:  net_new = lrelu((agg*dnorm) @ W + b) ----------------
__global__ __launch_bounds__(256) void pins_net_kernel(const float* __restrict__ agg, const float* __restrict__ dnorm,
                                                       const float* __restrict__ W, const float* __restrict__ B,
                                                       float* __restrict__ Y, int n)
{
    __shared__ float Ws[64 * 64], bs[64], Xs[4 * 64];
    for (int i = threadIdx.x; i < 64 * 64; i += 256) Ws[i] = W[i];
    if (threadIdx.x < 64) bs[threadIdx.x] = B[threadIdx.x];
    __syncthreads();
    const int r = threadIdx.x >> 6, c = threadIdx.x & 63;
    for (int base = blockIdx.x * 4; base < n; base += gridDim.x * 4) {
        __syncthreads();
        {
            int row = base + (threadIdx.x >> 6);
            Xs[threadIdx.x] = (row < n) ? agg[(size_t)row * 64 + c] * dnorm[row] : 0.f;
        }
        __syncthreads();
        int row = base + r;
        if (row < n) {
            float acc = bs[c];
            #pragma unroll
            for (int k = 0; k < 64; k++) acc += Xs[r * 64 + k] * Ws[k * 64 + c];
            Y[(size_t)row * 64 + c] = lrelu_(acc);
        }
    }
}

// ---------------- CFConv fused per-pin kernel ----------------
__global__ __launch_bounds__(256) void cf_pin_kernel(const float* __restrict__ pinf, const float* __restrict__ hv,
                                                     const int* __restrict__ psrc, const int* __restrict__ pdst,
                                                     const float* __restrict__ W1, const float* __restrict__ B1,
                                                     const float* __restrict__ W2, const float* __restrict__ B2,
                                                     float* __restrict__ h_cf, int np)
{
    __shared__ float Ws1[16 * 64], Ws2[64 * 64], bs1[64], bs2[64];
    __shared__ float PF[4 * 16], T1[4 * 64];
    for (int i = threadIdx.x; i < 16 * 64; i += 256) Ws1[i] = W1[i];
    for (int i = threadIdx.x; i < 64 * 64; i += 256) Ws2[i] = W2[i];
    if (threadIdx.x < 64) { bs1[threadIdx.x] = B1[threadIdx.x]; bs2[threadIdx.x] = B2[threadIdx.x]; }
    __syncthreads();
    const int r = threadIdx.x >> 6, c = threadIdx.x & 63;
    for (int base = blockIdx.x * 4; base < np; base += gridDim.x * 4) {
        __syncthreads();
        if (threadIdx.x < 64) {
            int row = base + (threadIdx.x >> 4);
            PF[threadIdx.x] = (row < np) ? pinf[(size_t)row * 16 + (threadIdx.x & 15)] : 0.f;
        }
        __syncthreads();
        float a = bs1[c];
        #pragma unroll
        for (int k = 0; k < 16; k++) a += PF[r * 16 + k] * Ws1[k * 64 + c];
        T1[r * 64 + c] = ssp_(a);
        __syncthreads();
        int p = base + r;
        if (p < np) {
            float b = bs2[c];
            #pragma unroll
            for (int k = 0; k < 64; k++) b += T1[r * 64 + k] * Ws2[k * 64 + c];
            float he = ssp_(b);
            int d = pdst[p], s = psrc[p];
            float m = hv[(size_t)d * 64 + c] * he;
            unsafeAtomicAdd(&h_cf[(size_t)s * 64 + c], m);
        }
    }
}

// ---------------- SAGE edge scatter-max ----------------
__global__ __launch_bounds__(256) void sage_edge_kernel(const float* __restrict__ hp, const float* __restrict__ ew,
                                                        const int* __restrict__ esrc, const int* __restrict__ edst,
                                                        unsigned int* __restrict__ h_ng, int ne)
{
    long long idx = (long long)blockIdx.x * 256 + threadIdx.x;
    int e = (int)(idx >> 6); if (e >= ne) return;
    int c = (int)(idx & 63);
    int s = esrc[e], d = edst[e];
    float v = hp[(size_t)s * 64 + c] * ew[e];   // v >= 0 always
    atomicMax(&h_ng[(size_t)d * 64 + c], __float_as_uint(v));
}

// ---------------- combine: node_new = lrelu(max(ssp(h_cf@Wc+bc), nf@Ws + h_ng@Wn + sb)) ----------------
__global__ __launch_bounds__(256) void combine_kernel(const float* __restrict__ h_cf, const float* __restrict__ nf,
                                                      const float* __restrict__ h_ng,
                                                      const float* __restrict__ cW, const float* __restrict__ cB,
                                                      const float* __restrict__ sW, const float* __restrict__ nW,
                                                      const float* __restrict__ sB,
                                                      float* __restrict__ out, int n)
{
    __shared__ float Wc[64 * 64], Wsf[64 * 64], Wng[64 * 64], bc[64], bsg[64];
    __shared__ float Xc[4 * 64], Xf[4 * 64], Xn[4 * 64];
    for (int i = threadIdx.x; i < 64 * 64; i += 256) {
        Wc[i] = cW[i]; Wsf[i] = sW[i]; Wng[i] = nW[i];
    }
    if (threadIdx.x < 64) { bc[threadIdx.x] = cB[threadIdx.x]; bsg[threadIdx.x] = sB[threadIdx.x]; }
    __syncthreads();
    const int r = threadIdx.x >> 6, c = threadIdx.x & 63;
    for (int base = blockIdx.x * 4; base < n; base += gridDim.x * 4) {
        __syncthreads();
        {
            int row = base + (threadIdx.x >> 6);
            size_t off = (size_t)row * 64 + c;
            bool ok = row < n;
            Xc[threadIdx.x] = ok ? h_cf[off] : 0.f;
            Xf[threadIdx.x] = ok ? nf[off] : 0.f;
            Xn[threadIdx.x] = ok ? h_ng[off] : 0.f;
        }
        __syncthreads();
        int row = base + r;
        if (row < n) {
            float a1 = bc[c], a2 = bsg[c];
            #pragma unroll
            for (int k = 0; k < 64; k++) {
                a1 += Xc[r * 64 + k] * Wc[k * 64 + c];
                a2 += Xf[r * 64 + k] * Wsf[k * 64 + c] + Xn[r * 64 + k] * Wng[k * 64 + c];
            }
            float cf = ssp_(a1);
            out[(size_t)row * 64 + c] = lrelu_(fmaxf(cf, a2));
        }
    }
}

// ---------------- output heads ----------------
__global__ __launch_bounds__(256) void node_head_kernel(const float* __restrict__ in_node, const float* __restrict__ nf,
                                                        const float* __restrict__ W1, const float* __restrict__ B1,
                                                        const float* __restrict__ W2, const float* __restrict__ B2,
                                                        const float* __restrict__ W3, const float* __restrict__ B3,
                                                        float* __restrict__ out, int n)
{
    __shared__ float Ws1[80 * 64], Ws2[64 * 64], Ws3[64 * 4], bs1[64], bs2[64], bs3[4];
    __shared__ float Xs[4 * 80], H1[4 * 64], H2[4 * 64];
    for (int i = threadIdx.x; i < 80 * 64; i += 256) Ws1[i] = W1[i];
    for (int i = threadIdx.x; i < 64 * 64; i += 256) Ws2[i] = W2[i];
    for (int i = threadIdx.x; i < 64 * 4; i += 256) Ws3[i] = W3[i];
    if (threadIdx.x < 64) { bs1[threadIdx.x] = B1[threadIdx.x]; bs2[threadIdx.x] = B2[threadIdx.x]; }
    if (threadIdx.x < 4) bs3[threadIdx.x] = B3[threadIdx.x];
    __syncthreads();
    const int r = threadIdx.x >> 6, c = threadIdx.x & 63;
    for (int base = blockIdx.x * 4; base < n; base += gridDim.x * 4) {
        __syncthreads();
        for (int i = threadIdx.x; i < 4 * 80; i += 256) {
            int row = base + i / 80, k = i % 80;
            float v = 0.f;
            if (row < n) v = (k < 16) ? in_node[(size_t)row * 16 + k] : nf[(size_t)row * 64 + (k - 16)];
            Xs[i] = v;
        }
        __syncthreads();
        float a = bs1[c];
        #pragma unroll
        for (int k = 0; k < 80; k++) a += Xs[r * 80 + k] * Ws1[k * 64 + c];
        H1[r * 64 + c] = lrelu_(a);
        __syncthreads();
        float a2 = bs2[c];
        #pragma unroll
        for (int k = 0; k < 64; k++) a2 += H1[r * 64 + k] * Ws2[k * 64 + c];
        H2[r * 64 + c] = lrelu_(a2);
        __syncthreads();
        int row = base + r;
        if (row < n && c < 4) {
            float a3 = bs3[c];
            #pragma unroll
            for (int k = 0; k < 64; k++) a3 += H2[r * 64 + k] * Ws3[k * 4 + c];
            out[(size_t)row * 4 + c] = sigm_(a3);
        }
    }
}

__global__ __launch_bounds__(256) void net_head_kernel(const float* __restrict__ in_net, const float* __restrict__ tf,
                                                       const float* __restrict__ W1, const float* __restrict__ B1,
                                                       const float* __restrict__ W2, const float* __restrict__ B2,
                                                       const float* __restrict__ W3, const float* __restrict__ B3,
                                                       float* __restrict__ out, int n)
{
    __shared__ float Ws1[72 * 64], Ws2[64 * 64], Ws3[64], bs1[64], bs2[64], bs3[1];
    __shared__ float Xs[4 * 72], H1[4 * 64], H2[4 * 64];
    for (int i = threadIdx.x; i < 72 * 64; i += 256) Ws1[i] = W1[i];
    for (int i = threadIdx.x; i < 64 * 64; i += 256) Ws2[i] = W2[i];
    if (threadIdx.x < 64) { Ws3[threadIdx.x] = W3[threadIdx.x]; bs1[threadIdx.x] = B1[threadIdx.x]; bs2[threadIdx.x] = B2[threadIdx.x]; }
    if (threadIdx.x == 0) bs3[0] = B3[0];
    __syncthreads();
    const int r = threadIdx.x >> 6, c = threadIdx.x & 63;
    for (int base = blockIdx.x * 4; base < n; base += gridDim.x * 4) {
        __syncthreads();
        for (int i = threadIdx.x; i < 4 * 72; i += 256) {
            int row = base + i / 72, k = i % 72;
            float v = 0.f;
            if (row < n) v = (k < 8) ? in_net[(size_t)row * 8 + k] : tf[(size_t)row * 64 + (k - 8)];
            Xs[i] = v;
        }
        __syncthreads();
        float a = bs1[c];
        #pragma unroll
        for (int k = 0; k < 72; k++) a += Xs[r * 72 + k] * Ws1[k * 64 + c];
        H1[r * 64 + c] = lrelu_(a);
        __syncthreads();
        float a2 = bs2[c];
        #pragma unroll
        for (int k = 0; k < 64; k++) a2 += H1[r * 64 + k] * Ws2[k * 64 + c];
        H2[r * 64 + c] = lrelu_(a2);
        __syncthreads();
        int row = base + r;
        if (row < n && c == 0) {
            float a3 = bs3[0];
            #pragma unroll
            for (int k = 0; k < 64; k++) a3 += H2[r * 64 + k] * Ws3[k];
            out[row] = sigm_(a3);
        }
    }
}

extern "C" void kernel_launch(void* const* d_in, const int* in_sizes, int n_in,
                              void* d_out, int out_size, void* d_ws, size_t ws_size,
                              hipStream_t stream)
{
    (void)in_sizes; (void)n_in; (void)out_size; (void)ws_size;
    constexpr int Nn = 100000, Nt = 30000, Np = 400000, Ne = 1000000;
    constexpr int H = 64, L = 3, T = 4;

    auto fpt = [&](int i){ return (const float*)d_in[i]; };
    auto ipt = [&](int i){ return (const int*)d_in[i]; };

    const float* in_node = fpt(0);
    const float* in_net  = fpt(1);
    const float* in_pin  = fpt(2);
    const float* in_edge = fpt(3);
    const int* psrc = ipt(4);
    const int* pdst = ipt(5);
    const int* esrc = ipt(6);
    const int* edst = ipt(7);

    float* ws = (float*)d_ws;
    size_t o = 0;
    auto alloc = [&](size_t nel){ float* p = ws + o; o += nel; return p; };
    float* node_a = alloc((size_t)Nn * H);
    float* node_b = alloc((size_t)Nn * H);
    float* net_a  = alloc((size_t)Nt * H);
    float* net_b  = alloc((size_t)Nt * H);
    float* agg    = alloc((size_t)Nt * H);
    float* hv     = alloc((size_t)Nt * H);
    float* pinf   = alloc((size_t)Np * 16);
    float* h_cf   = alloc((size_t)Nn * H);
    float* hp     = alloc((size_t)Nn * H);
    float* h_ng   = alloc((size_t)Nn * H);
    float* ew3    = alloc((size_t)3 * Ne);
    float* snorm  = alloc((size_t)Nn);
    float* dnorm  = alloc((size_t)Nt);

    // degree norms
    hipMemsetAsync(snorm, 0, (size_t)Nn * 4, stream);
    hipMemsetAsync(dnorm, 0, (size_t)Nt * 4, stream);
    deg_kernel<<<(Np + 255) / 256, 256, 0, stream>>>(psrc, pdst, (int*)snorm, (int*)dnorm, Np);
    norm_kernel<<<(Nn + 255) / 256, 256, 0, stream>>>((int*)snorm, Nn);
    norm_kernel<<<(Nt + 255) / 256, 256, 0, stream>>>((int*)dnorm, Nt);

    // input encoders
    lin_kernel<16, 64, 1><<<2048, 256, 0, stream>>>(in_node, fpt(8),  fpt(9),  node_a, Nn);
    lin_kernel< 8, 64, 1><<<1024, 256, 0, stream>>>(in_net,  fpt(10), fpt(11), net_a,  Nt);
    lin_kernel< 8, 16, 1><<<2048, 256, 0, stream>>>(in_pin,  fpt(12), fpt(13), pinf,   Np);
    edge_ew_kernel<<<2048, 256, 0, stream>>>(in_edge, fpt(14), fpt(15), fpt(16), fpt(17), ew3, Ne);

    float* ncur = node_a; float* nnew = node_b;
    float* tcur = net_a;  float* tnew = net_b;

    for (int i = 0; i < L; i++) {
        // pins GraphConv (node -> net)
        hipMemsetAsync(agg, 0, (size_t)Nt * H * 4, stream);
        pins_scatter<<<(Np * 64 + 255) / 256, 256, 0, stream>>>(ncur, snorm, psrc, pdst, agg, Np);
        pins_net_kernel<<<1024, 256, 0, stream>>>(agg, dnorm, fpt(18) + (size_t)i * 4096, fpt(19) + (size_t)i * 64, tnew, Nt);

        // CFConv (net -> node)
        lin_kernel<64, 64, 0><<<1024, 256, 0, stream>>>(tcur, fpt(20) + (size_t)i * 4096, fpt(21) + (size_t)i * 64, hv, Nt);
        hipMemsetAsync(h_cf, 0, (size_t)Nn * H * 4, stream);
        cf_pin_kernel<<<4096, 256, 0, stream>>>(pinf, hv, psrc, pdst,
                                                fpt(22) + (size_t)i * 1024, fpt(23) + (size_t)i * 64,
                                                fpt(24) + (size_t)i * 4096, fpt(25) + (size_t)i * 64,
                                                h_cf, Np);

        // SAGE (near)
        lin_kernel<64, 64, 2><<<2048, 256, 0, stream>>>(ncur, fpt(28) + (size_t)i * 4096, fpt(29) + (size_t)i * 64, hp, Nn);
        hipMemsetAsync(h_ng, 0, (size_t)Nn * H * 4, stream);
        sage_edge_kernel<<<(int)(((long long)Ne * 64 + 255) / 256), 256, 0, stream>>>(hp, ew3 + (size_t)i * Ne, esrc, edst, (unsigned int*)h_ng, Ne);

        // combine + activations
        combine_kernel<<<2048, 256, 0, stream>>>(h_cf, ncur, h_ng,
                                                 fpt(26) + (size_t)i * 4096, fpt(27) + (size_t)i * 64,
                                                 fpt(30) + (size_t)i * 4096, fpt(31) + (size_t)i * 4096,
                                                 fpt(32) + (size_t)i * 64,
                                                 nnew, Nn);
        float* t;
        t = ncur; ncur = nnew; nnew = t;
        t = tcur; tcur = tnew; tnew = t;
    }

    float* out = (float*)d_out;
    node_head_kernel<<<2048, 256, 0, stream>>>(in_node, ncur, fpt(33), fpt(34), fpt(35), fpt(36), fpt(37), fpt(38), out, Nn);
    net_head_kernel<<<1024, 256, 0, stream>>>(in_net, tcur, fpt(39), fpt(40), fpt(41), fpt(42), fpt(43), fpt(44), out + (size_t)Nn * T, Nt);
}